// Round 3
// baseline (994.961 us; speedup 1.0000x reference)
//
#include <hip/hip_runtime.h>

#define NN      20
#define FF      2764800            // 3*720*1280
#define TK      64                 // k-tile (floats)
#define NROWS   40                 // 20 rows clip2 + 20 rows clip1
#define NTILES  (FF / TK)          // 43200
#define GRID    2048               // 8 blocks/CU * 256 CUs
#define NTHREADS 256
#define PADK    72                 // LDS row stride: start bank = (8*row + 4*slice) mod 32 -> 2-way max (free)

// ws layout (floats): nrep replicas of 440:
//   [rep*440 + 0..399]   cross[i*20+j] partials
//   [rep*440 + 400..419] q2[i]
//   [rep*440 + 420..439] q1[j]

__global__ void zero_ws_kernel(float* __restrict__ ws, int n) {
    int i = blockIdx.x * blockDim.x + threadIdx.x;
    if (i < n) ws[i] = 0.0f;
}

__global__ __launch_bounds__(NTHREADS, 8) void gram_kernel(
    const float* __restrict__ clip1,
    const float* __restrict__ clip2,
    float* __restrict__ ws,
    int repMask)
{
    __shared__ float s[NROWS][PADK];        // 11,520 B

    const int tid   = threadIdx.x;
    const int slice = tid >> 4;             // 0..15 == k-chunk index within tile
    const int sub   = tid & 15;
    const int gi    = sub >> 2;             // 0..3   (i = gi + 4*ri, ri 0..4)
    const int gj    = sub & 3;              // 0..3   (j = gj + 4*rj, rj 0..4)
    const int k0    = slice * 4;            // float offset of this thread's chunk

    float acc[5][5];
    #pragma unroll
    for (int a = 0; a < 5; ++a)
        #pragma unroll
        for (int b = 0; b < 5; ++b) acc[a][b] = 0.0f;
    float sq[5] = {0.f, 0.f, 0.f, 0.f, 0.f};

    // staging map: idx = tid + 256*r -> row = idx>>5 (0..39), float2 off = (idx&31)*2
    const float* srow[5];
    int foff[5];
    int rown[5];
    #pragma unroll
    for (int r = 0; r < 5; ++r) {
        int idx = tid + NTHREADS * r;
        int row = idx >> 5;
        rown[r] = row;
        foff[r] = (idx & 31) * 2;
        srow[r] = (row < NN) ? (clip2 + (size_t)row * FF)
                             : (clip1 + (size_t)(row - NN) * FF);
    }

    // contiguous K-span for this block: tiles [t0, t1)
    const int t0 = (int)(((long long)blockIdx.x * NTILES) / GRID);
    const int t1 = (int)(((long long)(blockIdx.x + 1) * NTILES) / GRID);

    // prologue: load first tile into registers
    float2 v[5];
    {
        size_t kb = (size_t)t0 * TK;
        #pragma unroll
        for (int r = 0; r < 5; ++r)
            v[r] = *(const float2*)(srow[r] + kb + foff[r]);
    }

    for (int t = t0; t < t1; ++t) {
        // stage current tile + accumulate squares from registers
        #pragma unroll
        for (int r = 0; r < 5; ++r) {
            *(float2*)&s[rown[r]][foff[r]] = v[r];
            sq[r] += v[r].x * v[r].x + v[r].y * v[r].y;
        }
        __syncthreads();

        // prefetch next (sequential) tile — overlaps with compute below
        if (t + 1 < t1) {
            size_t kb = (size_t)(t + 1) * TK;
            #pragma unroll
            for (int r = 0; r < 5; ++r)
                v[r] = *(const float2*)(srow[r] + kb + foff[r]);
        }

        // compute: 5x5 output pairs, i = gi+4ri, j = gj+4rj
        float4 av[5];
        #pragma unroll
        for (int ri = 0; ri < 5; ++ri)
            av[ri] = *(const float4*)&s[gi + 4 * ri][k0];
        #pragma unroll
        for (int rj = 0; rj < 5; ++rj) {
            float4 bv = *(const float4*)&s[NN + gj + 4 * rj][k0];
            #pragma unroll
            for (int ri = 0; ri < 5; ++ri) {
                acc[ri][rj] += av[ri].x * bv.x;
                acc[ri][rj] += av[ri].y * bv.y;
                acc[ri][rj] += av[ri].z * bv.z;
                acc[ri][rj] += av[ri].w * bv.w;
            }
        }
        __syncthreads();
    }

    float* wsr = ws + (blockIdx.x & repMask) * 440;

    // ---- reduce cross partials over the 4 slices within each wave ----
    // lanes with equal (lane&15) share (gi,gj); wave-local slices differ at strides 16,32
    #pragma unroll
    for (int a = 0; a < 5; ++a)
        #pragma unroll
        for (int b = 0; b < 5; ++b) {
            float vsum = acc[a][b];
            vsum += __shfl_down(vsum, 32);
            vsum += __shfl_down(vsum, 16);
            acc[a][b] = vsum;              // valid on lanes 0..15
        }

    float* red = &s[0][0];                 // reuse LDS: 4 waves * 16 subs * 25 = 1600 floats
    const int lane = tid & 63;
    const int wv   = tid >> 6;
    if (lane < 16) {
        #pragma unroll
        for (int a = 0; a < 5; ++a)
            #pragma unroll
            for (int b = 0; b < 5; ++b)
                red[(wv * 16 + lane) * 25 + a * 5 + b] = acc[a][b];
    }
    __syncthreads();

    for (int p = tid; p < 400; p += NTHREADS) {
        int psub = p / 25;                 // 0..15
        int rem  = p % 25;
        int pa   = rem / 5;                // ri 0..4
        int pb   = rem % 5;                // rj 0..4
        float vsum = red[(0 * 16 + psub) * 25 + rem]
                   + red[(1 * 16 + psub) * 25 + rem]
                   + red[(2 * 16 + psub) * 25 + rem]
                   + red[(3 * 16 + psub) * 25 + rem];
        int i = (psub >> 2) + 4 * pa;
        int j = (psub & 3) + 4 * pb;
        atomicAdd(&wsr[i * NN + j], vsum);
    }

    // ---- reduce squares: threads in each aligned 32-lane group share a row ----
    #pragma unroll
    for (int r = 0; r < 5; ++r) {
        float vq = sq[r];
        vq += __shfl_down(vq, 16, 32);
        vq += __shfl_down(vq, 8, 32);
        vq += __shfl_down(vq, 4, 32);
        vq += __shfl_down(vq, 2, 32);
        vq += __shfl_down(vq, 1, 32);
        if ((tid & 31) == 0) {
            int row = (tid + NTHREADS * r) >> 5;   // 0..39
            atomicAdd(&wsr[400 + row], vq);
        }
    }
}

__global__ void finalize_kernel(const float* __restrict__ ws, float* __restrict__ out,
                                int nrep) {
    int d = threadIdx.x;
    if (d >= 21) return;
    int k  = d - 10;                    // diagonal offset (col - row)
    int a  = k < 0 ? -k : k;
    int i0 = k < 0 ? -k : 0;
    int L  = NN - a;
    const float invF = 1.0f / (float)FF;
    float sum = 0.0f;
    for (int m = 0; m < L; ++m) {
        int i = i0 + m;
        int j = i + k;
        float q2 = 0.f, q1 = 0.f, cr = 0.f;
        for (int rep = 0; rep < nrep; ++rep) {
            const float* w = ws + rep * 440;
            q2 += w[400 + i];
            q1 += w[420 + j];
            cr += w[i * NN + j];
        }
        sum += q2 + q1 - 2.0f * cr;     // sum over k of (c2-c1)^2, scaled by F
    }
    out[d] = -(sum * invF / (float)L) * 1e13f;
}

extern "C" void kernel_launch(void* const* d_in, const int* in_sizes, int n_in,
                              void* d_out, int out_size, void* d_ws, size_t ws_size,
                              hipStream_t stream) {
    const float* clip1 = (const float*)d_in[0];
    const float* clip2 = (const float*)d_in[1];
    float* out = (float*)d_out;
    float* ws  = (float*)d_ws;

    int nrep = (ws_size >= (size_t)(8 * 440) * sizeof(float)) ? 8 : 1;
    int nz = nrep * 440;
    zero_ws_kernel<<<(nz + 255) / 256, 256, 0, stream>>>(ws, nz);
    gram_kernel<<<GRID, NTHREADS, 0, stream>>>(clip1, clip2, ws, nrep - 1);
    finalize_kernel<<<1, 64, 0, stream>>>(ws, out, nrep);
}

// Round 4
// 141.828 us; speedup vs baseline: 7.0152x; 7.0152x over previous
//
#include <hip/hip_runtime.h>

#define NN      20
#define FF      2764800            // 3*720*1280
#define TK      64                 // k-floats per tile per wave
#define NROWS   40                 // 20 rows clip2 + 20 rows clip1
#define NTILES  (FF / TK)          // 43200
#define NBLK    768                // 3 blocks/CU (LDS-capped: 46KB/block)
#define NTHREADS 256
#define NW      (NBLK * 4)         // 3072 waves, strided tile ownership
#define PAD4    18                 // LDS row stride in float4 units (72 floats)

// ws layout (floats): nrep replicas of 440:
//   [rep*440 + 0..399]   cross[i*20+j]
//   [rep*440 + 400..419] q2[i]     (row i of clip2)
//   [rep*440 + 420..439] q1[j]     (row j of clip1)

__global__ void zero_ws_kernel(float* __restrict__ ws, int n) {
    int i = blockIdx.x * blockDim.x + threadIdx.x;
    if (i < n) ws[i] = 0.0f;
}

__global__ __launch_bounds__(NTHREADS, 3) void gram_kernel(
    const float* __restrict__ clip1,
    const float* __restrict__ clip2,
    float* __restrict__ ws,
    int repMask)
{
    // one private tile buffer per wave: 40 rows x 72 floats = 11520 B; x4 waves
    __shared__ float s[4][NROWS * PAD4 * 4];

    const int tid  = threadIdx.x;
    const int lane = tid & 63;
    const int wv   = tid >> 6;
    const int sub  = lane & 15;
    const int kq   = lane >> 4;            // 0..3: 16-float k-chunk within tile
    const int gi   = sub >> 2;             // i = gi + 4*ri
    const int gj   = sub & 3;              // j = gj + 4*rj

    float4* const S4 = (float4*)&s[wv][0];

    // staging map (r = 0..9): idx = lane + 64r -> row = (lane>>4)+4r, c4 = lane&15
    const float* gp[10];                   // per-lane global source (float ptr)
    float4*      wp[10];                   // per-lane LDS dest (float4 slot)
    #pragma unroll
    for (int r = 0; r < 10; ++r) {
        int row = (lane >> 4) + 4 * r;
        const float* base = (row < NN) ? (clip2 + (size_t)row * FF)
                                       : (clip1 + (size_t)(row - NN) * FF);
        gp[r] = base + (lane & 15) * 4;
        wp[r] = S4 + row * PAD4 + (lane & 15);
    }

    // per-lane LDS read bases: A rows gi+4ri (clip2), B rows 20+gj+4rj (clip1)
    const float4* ra[5];
    const float4* rb[5];
    #pragma unroll
    for (int r5 = 0; r5 < 5; ++r5) {
        ra[r5] = S4 + (gi + 4 * r5) * PAD4 + 4 * kq;
        rb[r5] = S4 + (NN + gj + 4 * r5) * PAD4 + 4 * kq;
    }

    float acc[5][5];
    #pragma unroll
    for (int a = 0; a < 5; ++a)
        #pragma unroll
        for (int b = 0; b < 5; ++b) acc[a][b] = 0.0f;
    float sq[10];
    #pragma unroll
    for (int r = 0; r < 10; ++r) sq[r] = 0.0f;

    const int W = blockIdx.x * 4 + wv;     // global wave id; tiles W, W+NW, ...
    int t = W;

    float4 v[10];
    #pragma unroll
    for (int r = 0; r < 10; ++r)
        v[r] = *(const float4*)(gp[r] + (size_t)t * TK);

    while (t < NTILES) {
        const int tn = t + NW;

        // stage tile t into private LDS; squares from registers
        #pragma unroll
        for (int r = 0; r < 10; ++r) {
            *wp[r] = v[r];
            sq[r] += v[r].x * v[r].x + v[r].y * v[r].y
                   + v[r].z * v[r].z + v[r].w * v[r].w;
        }

        // issue next tile's loads — latency hidden under compute below
        if (tn < NTILES) {
            #pragma unroll
            for (int r = 0; r < 10; ++r)
                v[r] = *(const float4*)(gp[r] + (size_t)tn * TK);
        }

        // compute 5x5 cross products on this wave's 16-float k-chunk
        #pragma unroll
        for (int q = 0; q < 4; ++q) {
            float4 a5[5], b5[5];
            #pragma unroll
            for (int x = 0; x < 5; ++x) { a5[x] = ra[x][q]; b5[x] = rb[x][q]; }
            #pragma unroll
            for (int ri = 0; ri < 5; ++ri)
                #pragma unroll
                for (int rj = 0; rj < 5; ++rj) {
                    acc[ri][rj] += a5[ri].x * b5[rj].x;
                    acc[ri][rj] += a5[ri].y * b5[rj].y;
                    acc[ri][rj] += a5[ri].z * b5[rj].z;
                    acc[ri][rj] += a5[ri].w * b5[rj].w;
                }
        }
        t = tn;
    }

    float* wsr = ws + (blockIdx.x & repMask) * 440;

    // ---- reduce cross over kq (lane bits 4,5) ----
    #pragma unroll
    for (int a = 0; a < 5; ++a)
        #pragma unroll
        for (int b = 0; b < 5; ++b) {
            float vsum = acc[a][b];
            vsum += __shfl_down(vsum, 32);
            vsum += __shfl_down(vsum, 16);
            acc[a][b] = vsum;              // valid on lanes 0..15
        }

    __syncthreads();                       // all waves done with tile buffers
    float* red = &s[0][0];                 // 4 waves * 16 subs * 25 = 1600 floats
    if (lane < 16) {
        #pragma unroll
        for (int a = 0; a < 5; ++a)
            #pragma unroll
            for (int b = 0; b < 5; ++b)
                red[(wv * 16 + lane) * 25 + a * 5 + b] = acc[a][b];
    }
    __syncthreads();

    for (int p = tid; p < 400; p += NTHREADS) {
        int psub = p / 25;
        int rem  = p % 25;
        int pa   = rem / 5;
        int pb   = rem % 5;
        float vsum = red[(0 * 16 + psub) * 25 + rem]
                   + red[(1 * 16 + psub) * 25 + rem]
                   + red[(2 * 16 + psub) * 25 + rem]
                   + red[(3 * 16 + psub) * 25 + rem];
        int i = (psub >> 2) + 4 * pa;
        int j = (psub & 3) + 4 * pb;
        atomicAdd(&wsr[i * NN + j], vsum);
    }

    // ---- reduce squares within each aligned 16-lane group (same lane>>4) ----
    #pragma unroll
    for (int r = 0; r < 10; ++r) {
        float vq = sq[r];
        vq += __shfl_xor(vq, 8);
        vq += __shfl_xor(vq, 4);
        vq += __shfl_xor(vq, 2);
        vq += __shfl_xor(vq, 1);
        if ((lane & 15) == 0) {
            int row = (lane >> 4) + 4 * r;        // 0..39
            atomicAdd(&wsr[400 + row], vq);       // 400+row covers q2 then q1
        }
    }
}

__global__ void finalize_kernel(const float* __restrict__ ws, float* __restrict__ out,
                                int nrep) {
    int d = threadIdx.x;
    if (d >= 21) return;
    int k  = d - 10;                    // diagonal offset (col - row)
    int a  = k < 0 ? -k : k;
    int i0 = k < 0 ? -k : 0;
    int L  = NN - a;
    const float invF = 1.0f / (float)FF;
    float sum = 0.0f;
    for (int m = 0; m < L; ++m) {
        int i = i0 + m;
        int j = i + k;
        float q2 = 0.f, q1 = 0.f, cr = 0.f;
        for (int rep = 0; rep < nrep; ++rep) {
            const float* w = ws + rep * 440;
            q2 += w[400 + i];
            q1 += w[420 + j];
            cr += w[i * NN + j];
        }
        sum += q2 + q1 - 2.0f * cr;
    }
    out[d] = -(sum * invF / (float)L) * 1e13f;
}

extern "C" void kernel_launch(void* const* d_in, const int* in_sizes, int n_in,
                              void* d_out, int out_size, void* d_ws, size_t ws_size,
                              hipStream_t stream) {
    const float* clip1 = (const float*)d_in[0];
    const float* clip2 = (const float*)d_in[1];
    float* out = (float*)d_out;
    float* ws  = (float*)d_ws;

    int nrep = 1;
    while (nrep < 16 && (size_t)(nrep * 2) * 440 * sizeof(float) <= ws_size)
        nrep *= 2;

    int nz = nrep * 440;
    zero_ws_kernel<<<(nz + 255) / 256, 256, 0, stream>>>(ws, nz);
    gram_kernel<<<NBLK, NTHREADS, 0, stream>>>(clip1, clip2, ws, nrep - 1);
    finalize_kernel<<<1, 64, 0, stream>>>(ws, out, nrep);
}

// Round 5
// 141.027 us; speedup vs baseline: 7.0551x; 1.0057x over previous
//
#include <hip/hip_runtime.h>

#define NN      20
#define FF      2764800            // 3*720*1280
#define TK      64                 // k-floats per tile per wave
#define NROWS   40                 // 20 rows clip2 + 20 rows clip1
#define NTILES  (FF / TK)          // 43200
#define NBLK    768                // 3 blocks/CU (LDS-capped)
#define NTHREADS 256
#define NW      (NBLK * 4)         // 3072 waves, strided tile ownership
#define PAD4    17                 // LDS row stride in float4 units (68 floats, ODD)
// bank granule of compute read = (row + 4*kq + q) mod 8 -> all 8 granules 2x = free

// ws layout (floats): nrep replicas of 440:
//   [rep*440 + 0..399]   cross[i*20+j]
//   [rep*440 + 400..419] q2[i]     (row i of clip2)
//   [rep*440 + 420..439] q1[j]     (row j of clip1)

__global__ void zero_ws_kernel(float* __restrict__ ws, int n) {
    int i = blockIdx.x * blockDim.x + threadIdx.x;
    if (i < n) ws[i] = 0.0f;
}

__global__ __launch_bounds__(NTHREADS, 3) void gram_kernel(
    const float* __restrict__ clip1,
    const float* __restrict__ clip2,
    float* __restrict__ ws,
    int repMask)
{
    // one private tile buffer per wave: 40 rows x 68 floats = 10,880 B; x4 waves
    __shared__ float s[4][NROWS * PAD4 * 4];

    const int tid  = threadIdx.x;
    const int lane = tid & 63;
    const int wv   = tid >> 6;
    const int sub  = lane & 15;
    const int kq   = lane >> 4;            // 0..3: 16-float k-chunk within tile
    const int gi   = sub >> 2;             // i = gi + 4*ri
    const int gj   = sub & 3;              // j = gj + 4*rj

    float4* const S4 = (float4*)&s[wv][0];

    // staging map (r = 0..9): idx = lane + 64r -> row = (lane>>4)+4r, c4 = lane&15
    const float* gp[10];                   // per-lane global source (float ptr)
    float4*      wp[10];                   // per-lane LDS dest (float4 slot)
    #pragma unroll
    for (int r = 0; r < 10; ++r) {
        int row = (lane >> 4) + 4 * r;
        const float* base = (row < NN) ? (clip2 + (size_t)row * FF)
                                       : (clip1 + (size_t)(row - NN) * FF);
        gp[r] = base + (lane & 15) * 4;
        wp[r] = S4 + row * PAD4 + (lane & 15);
    }

    // per-lane LDS read bases: A rows gi+4ri (clip2), B rows 20+gj+4rj (clip1)
    const float4* ra[5];
    const float4* rb[5];
    #pragma unroll
    for (int r5 = 0; r5 < 5; ++r5) {
        ra[r5] = S4 + (gi + 4 * r5) * PAD4 + 4 * kq;
        rb[r5] = S4 + (NN + gj + 4 * r5) * PAD4 + 4 * kq;
    }

    float acc[5][5];
    #pragma unroll
    for (int a = 0; a < 5; ++a)
        #pragma unroll
        for (int b = 0; b < 5; ++b) acc[a][b] = 0.0f;
    float sq[10];
    #pragma unroll
    for (int r = 0; r < 10; ++r) sq[r] = 0.0f;

    const int W = blockIdx.x * 4 + wv;     // global wave id; tiles W, W+NW, ...
    int t = W;

    float4 v[10];
    #pragma unroll
    for (int r = 0; r < 10; ++r)
        v[r] = *(const float4*)(gp[r] + (size_t)t * TK);

    while (t < NTILES) {
        const int tn = t + NW;

        // stage tile t into private LDS; squares from registers
        #pragma unroll
        for (int r = 0; r < 10; ++r) {
            *wp[r] = v[r];
            sq[r] += v[r].x * v[r].x + v[r].y * v[r].y
                   + v[r].z * v[r].z + v[r].w * v[r].w;
        }

        // issue next tile's loads — latency hidden under compute below
        if (tn < NTILES) {
            #pragma unroll
            for (int r = 0; r < 10; ++r)
                v[r] = *(const float4*)(gp[r] + (size_t)tn * TK);
        }

        // compute 5x5 cross products on this wave's 16-float k-chunk
        #pragma unroll
        for (int q = 0; q < 4; ++q) {
            float4 a5[5], b5[5];
            #pragma unroll
            for (int x = 0; x < 5; ++x) { a5[x] = ra[x][q]; b5[x] = rb[x][q]; }
            #pragma unroll
            for (int ri = 0; ri < 5; ++ri)
                #pragma unroll
                for (int rj = 0; rj < 5; ++rj) {
                    acc[ri][rj] += a5[ri].x * b5[rj].x;
                    acc[ri][rj] += a5[ri].y * b5[rj].y;
                    acc[ri][rj] += a5[ri].z * b5[rj].z;
                    acc[ri][rj] += a5[ri].w * b5[rj].w;
                }
        }
        t = tn;
    }

    float* wsr = ws + (blockIdx.x & repMask) * 440;

    // ---- reduce cross over kq (lane bits 4,5) ----
    #pragma unroll
    for (int a = 0; a < 5; ++a)
        #pragma unroll
        for (int b = 0; b < 5; ++b) {
            float vsum = acc[a][b];
            vsum += __shfl_down(vsum, 32);
            vsum += __shfl_down(vsum, 16);
            acc[a][b] = vsum;              // valid on lanes 0..15
        }

    __syncthreads();                       // all waves done with tile buffers
    float* red = &s[0][0];                 // 4 waves * 16 subs * 25 = 1600 floats
    if (lane < 16) {
        #pragma unroll
        for (int a = 0; a < 5; ++a)
            #pragma unroll
            for (int b = 0; b < 5; ++b)
                red[(wv * 16 + lane) * 25 + a * 5 + b] = acc[a][b];
    }
    __syncthreads();

    for (int p = tid; p < 400; p += NTHREADS) {
        int psub = p / 25;
        int rem  = p % 25;
        int pa   = rem / 5;
        int pb   = rem % 5;
        float vsum = red[(0 * 16 + psub) * 25 + rem]
                   + red[(1 * 16 + psub) * 25 + rem]
                   + red[(2 * 16 + psub) * 25 + rem]
                   + red[(3 * 16 + psub) * 25 + rem];
        int i = (psub >> 2) + 4 * pa;
        int j = (psub & 3) + 4 * pb;
        atomicAdd(&wsr[i * NN + j], vsum);
    }

    // ---- reduce squares within each aligned 16-lane group (same lane>>4) ----
    #pragma unroll
    for (int r = 0; r < 10; ++r) {
        float vq = sq[r];
        vq += __shfl_xor(vq, 8);
        vq += __shfl_xor(vq, 4);
        vq += __shfl_xor(vq, 2);
        vq += __shfl_xor(vq, 1);
        if ((lane & 15) == 0) {
            int row = (lane >> 4) + 4 * r;        // 0..39
            atomicAdd(&wsr[400 + row], vq);       // 400+row covers q2 then q1
        }
    }
}

__global__ void finalize_kernel(const float* __restrict__ ws, float* __restrict__ out,
                                int nrep) {
    int d = threadIdx.x;
    if (d >= 21) return;
    int k  = d - 10;                    // diagonal offset (col - row)
    int a  = k < 0 ? -k : k;
    int i0 = k < 0 ? -k : 0;
    int L  = NN - a;
    const float invF = 1.0f / (float)FF;
    float sum = 0.0f;
    for (int m = 0; m < L; ++m) {
        int i = i0 + m;
        int j = i + k;
        float q2 = 0.f, q1 = 0.f, cr = 0.f;
        for (int rep = 0; rep < nrep; ++rep) {
            const float* w = ws + rep * 440;
            q2 += w[400 + i];
            q1 += w[420 + j];
            cr += w[i * NN + j];
        }
        sum += q2 + q1 - 2.0f * cr;
    }
    out[d] = -(sum * invF / (float)L) * 1e13f;
}

extern "C" void kernel_launch(void* const* d_in, const int* in_sizes, int n_in,
                              void* d_out, int out_size, void* d_ws, size_t ws_size,
                              hipStream_t stream) {
    const float* clip1 = (const float*)d_in[0];
    const float* clip2 = (const float*)d_in[1];
    float* out = (float*)d_out;
    float* ws  = (float*)d_ws;

    int nrep = 1;
    while (nrep < 16 && (size_t)(nrep * 2) * 440 * sizeof(float) <= ws_size)
        nrep *= 2;

    int nz = nrep * 440;
    zero_ws_kernel<<<(nz + 255) / 256, 256, 0, stream>>>(ws, nz);
    gram_kernel<<<NBLK, NTHREADS, 0, stream>>>(clip1, clip2, ws, nrep - 1);
    finalize_kernel<<<1, 64, 0, stream>>>(ws, out, nrep);
}